// Round 5
// baseline (657.243 us; speedup 1.0000x reference)
//
#include <hip/hip_runtime.h>
#include <hip/hip_bf16.h>
#include <math.h>

// Problem dims (fixed by reference)
#define Bq   8
#define Nq   16384
#define Dq   256
#define Eq   8
#define HIDq 128
#define KSEL 4096          // tokens per expert = N*TOPK/E
#define TOKENS (Bq * Nq)   // 131072

// out = 0.7 * dispatch + 0.0375   (alpha = 0.3)
#define SCALEq 0.7f
#define FLOORq 0.0375f

// ws layout (bytes). content/dvals are stored TRANSPOSED: [b][e][n]
#define CONT_OFF 0u
#define DIST_OFF 4194304u          // 1,048,576 f32
#define SUM_OFF  8388608u          // 1 double
#define TAU_OFF  (8388608u + 256u) // 64 u32
#define CUT_OFF  (8388608u + 512u) // 64 i32

// monotone map: float -> u32 such that float order == unsigned order
__device__ __forceinline__ unsigned key_of(float f) {
    unsigned u = __float_as_uint(f);
    return (u & 0x80000000u) ? ~u : (u | 0x80000000u);
}

// ---------------- kernel A: content logits + distances + fp64 dist-sum ----
__global__ __launch_bounds__(256, 2) void kA(
    const float* __restrict__ tokens, const float* __restrict__ xyz,
    const float* __restrict__ W1, const float* __restrict__ b1,
    const float* __restrict__ W2, const float* __restrict__ b2,
    const float* __restrict__ centers,
    float* __restrict__ content, float* __restrict__ dvals,
    double* __restrict__ sumd)
{
    const int tok = blockIdx.x * 256 + threadIdx.x;
    const int b   = tok >> 14;          // tok / Nq
    const int n   = tok & (Nq - 1);     // tok % Nq

    const float x0 = xyz[(size_t)tok * 3 + 0];
    const float x1 = xyz[(size_t)tok * 3 + 1];
    const float x2 = xyz[(size_t)tok * 3 + 2];

    // distances to 8 centers — exact f32 op order of the reference:
    // (dx*dx + dy*dy) + dz*dz, then sqrtf
    double local = 0.0;
    #pragma unroll
    for (int e = 0; e < Eq; ++e) {
        float dx = x0 - centers[e * 3 + 0];
        float dy = x1 - centers[e * 3 + 1];
        float dz = x2 - centers[e * 3 + 2];
        float s  = (dx * dx + dy * dy) + dz * dz;
        float dd = sqrtf(s);
        dvals[((size_t)b * Eq + e) * Nq + n] = dd;   // transposed store
        local += (double)dd;
    }

    // h = gate_input @ W1  (+ b1, zeros in practice but read anyway)
    float h[HIDq];
    #pragma unroll
    for (int j = 0; j < HIDq; ++j) h[j] = b1[j];

    const float* __restrict__ trow = tokens + (size_t)tok * Dq;
    for (int k = 0; k < Dq; k += 4) {
        const float4 xv = *reinterpret_cast<const float4*>(trow + k);
        const float* __restrict__ w = W1 + (size_t)k * HIDq;
        #pragma unroll
        for (int j = 0; j < HIDq; ++j) h[j] = fmaf(xv.x, w[j], h[j]);
        #pragma unroll
        for (int j = 0; j < HIDq; ++j) h[j] = fmaf(xv.y, w[HIDq + j], h[j]);
        #pragma unroll
        for (int j = 0; j < HIDq; ++j) h[j] = fmaf(xv.z, w[2 * HIDq + j], h[j]);
        #pragma unroll
        for (int j = 0; j < HIDq; ++j) h[j] = fmaf(xv.w, w[3 * HIDq + j], h[j]);
    }
    {   // gate_input dims 256..258 are spatial_xyz
        const float* __restrict__ w = W1 + (size_t)Dq * HIDq;
        #pragma unroll
        for (int j = 0; j < HIDq; ++j) h[j] = fmaf(x0, w[j], h[j]);
        #pragma unroll
        for (int j = 0; j < HIDq; ++j) h[j] = fmaf(x1, w[HIDq + j], h[j]);
        #pragma unroll
        for (int j = 0; j < HIDq; ++j) h[j] = fmaf(x2, w[2 * HIDq + j], h[j]);
    }

    // exact GELU + second GEMM
    float acc[Eq];
    #pragma unroll
    for (int e = 0; e < Eq; ++e) acc[e] = b2[e];
    #pragma unroll
    for (int j = 0; j < HIDq; ++j) {
        const float v = h[j];
        const float g = 0.5f * v * (1.0f + erff(v * 0.70710678118654752440f));
        #pragma unroll
        for (int e = 0; e < Eq; ++e)
            acc[e] = fmaf(g, W2[j * Eq + e], acc[e]);
    }
    #pragma unroll
    for (int e = 0; e < Eq; ++e)
        content[((size_t)b * Eq + e) * Nq + n] = acc[e];   // transposed store

    // block-reduce the fp64 distance sum, one atomicAdd per block
    #pragma unroll
    for (int off = 32; off > 0; off >>= 1)
        local += __shfl_down(local, off);
    __shared__ double lsum[4];
    const int lane = threadIdx.x & 63, wid = threadIdx.x >> 6;
    if (lane == 0) lsum[wid] = local;
    __syncthreads();
    if (threadIdx.x == 0)
        atomicAdd(sumd, lsum[0] + lsum[1] + lsum[2] + lsum[3]);
}

// ---------------- kernel B: exact k-th-largest select per (b,e) ----------
// LDS use ~2 KB; keys are recomputed from global each pass (L2-resident).
__global__ __launch_bounds__(256, 1) void kB(
    const float* __restrict__ content, const float* __restrict__ dvals,
    const double* __restrict__ sumd,
    unsigned* __restrict__ tau_out, int* __restrict__ cut_out)
{
    const int be = blockIdx.x;      // 0..63 == b*Eq + e

    __shared__ unsigned hist[256];
    __shared__ unsigned sufa[256];
    __shared__ unsigned sc[2];

    const float meanf = (float)(sumd[0] * (1.0 / (double)(Bq * Nq * Eq)));
    const float denom = meanf + 1e-6f;

    const float* __restrict__ ce = content + (size_t)be * Nq;
    const float* __restrict__ de = dvals   + (size_t)be * Nq;

    unsigned prefix = 0, mask = 0;
    int needed = KSEL;
    for (int pass = 0; pass < 4; ++pass) {
        const int shift = 24 - 8 * pass;
        hist[threadIdx.x] = 0;
        __syncthreads();
        for (int i = threadIdx.x; i < Nq; i += 256) {
            float aff = (-de[i]) / denom;       // identical expr everywhere
            float lg  = ce[i] + aff;
            unsigned kk = key_of(lg);
            if ((kk & mask) == prefix)
                atomicAdd(&hist[(kk >> shift) & 0xFFu], 1u);
        }
        __syncthreads();
        // suffix-sum: sufa[i] = count of keys with byte >= i
        sufa[threadIdx.x] = hist[threadIdx.x];
        __syncthreads();
        for (int st = 1; st < 256; st <<= 1) {
            unsigned v = sufa[threadIdx.x];
            unsigned a = (threadIdx.x + st < 256) ? sufa[threadIdx.x + st] : 0u;
            __syncthreads();
            sufa[threadIdx.x] = v + a;
            __syncthreads();
        }
        unsigned mine = sufa[threadIdx.x];
        unsigned hi   = (threadIdx.x < 255) ? sufa[threadIdx.x + 1] : 0u;
        if (mine >= (unsigned)needed && hi < (unsigned)needed) {
            sc[0] = (unsigned)threadIdx.x;       // selected bucket byte
            sc[1] = (unsigned)needed - hi;       // remaining needed inside it
        }
        __syncthreads();
        prefix |= sc[0] << shift;
        mask   |= 0xFFu << shift;
        needed  = (int)sc[1];
        __syncthreads();
    }

    // tie cutoff: index of the `needed`-th key == prefix, ascending index
    // (jax.lax.top_k breaks ties by lower index). wave 0 scans 64-wide chunks.
    if (threadIdx.x < 64) {
        const int lane = threadIdx.x;
        int running = 0, cut = Nq;
        for (int c = 0; c < Nq / 64; ++c) {
            float aff = (-de[c * 64 + lane]) / denom;
            float lg  = ce[c * 64 + lane] + aff;
            unsigned kk = key_of(lg);
            unsigned long long m = __ballot(kk == prefix);
            int cnt = __popcll(m);
            if (running + cnt >= needed) {
                int want = needed - running;     // 1-based within this chunk
                unsigned long long mm = m;
                for (int q = 1; q < want; ++q) mm &= (mm - 1ull);
                cut = c * 64 + (int)__builtin_ctzll(mm);
                break;
            }
            running += cnt;
        }
        if (lane == 0) { tau_out[be] = prefix; cut_out[be] = cut; }
    }
}

// ---------------- kernel C: write output --------------------------------
__global__ __launch_bounds__(256) void kC(
    const float* __restrict__ content, const float* __restrict__ dvals,
    const double* __restrict__ sumd,
    const unsigned* __restrict__ tau, const int* __restrict__ cut,
    float* __restrict__ out)
{
    const int idx = blockIdx.x * 256 + threadIdx.x;   // (b,n) flat
    const int b = idx >> 14;
    const int n = idx & (Nq - 1);

    const float meanf = (float)(sumd[0] * (1.0 / (double)(Bq * Nq * Eq)));
    const float denom = meanf + 1e-6f;

    #pragma unroll
    for (int e = 0; e < Eq; ++e) {
        const size_t bt = ((size_t)b * Eq + e) * Nq + n;  // transposed read
        float aff = (-dvals[bt]) / denom;
        float lg  = content[bt] + aff;             // identical expr to kB
        unsigned k  = key_of(lg);
        unsigned tk = tau[b * Eq + e];
        bool sel = (k > tk) || (k == tk && n <= cut[b * Eq + e]);
        float disp = sel ? (1.0f / (1.0f + expf(-lg))) : 0.0f;
        out[(size_t)idx * Eq + e] = fmaf(SCALEq, disp, FLOORq);
    }
}

extern "C" void kernel_launch(void* const* d_in, const int* in_sizes, int n_in,
                              void* d_out, int out_size, void* d_ws, size_t ws_size,
                              hipStream_t stream) {
    const float* tokens  = (const float*)d_in[0];
    const float* xyz     = (const float*)d_in[1];
    const float* W1      = (const float*)d_in[2];
    const float* b1      = (const float*)d_in[3];
    const float* W2      = (const float*)d_in[4];
    const float* b2      = (const float*)d_in[5];
    const float* centers = (const float*)d_in[6];
    // d_in[7] = t (unused by the reference computation)

    char* ws = (char*)d_ws;
    float*    content = (float*)(ws + CONT_OFF);
    float*    dvals   = (float*)(ws + DIST_OFF);
    double*   sumd    = (double*)(ws + SUM_OFF);
    unsigned* tau     = (unsigned*)(ws + TAU_OFF);
    int*      cutv    = (int*)(ws + CUT_OFF);

    hipMemsetAsync(sumd, 0, sizeof(double), stream);
    kA<<<TOKENS / 256, 256, 0, stream>>>(tokens, xyz, W1, b1, W2, b2, centers,
                                         content, dvals, sumd);
    kB<<<Bq * Eq, 256, 0, stream>>>(content, dvals, sumd, tau, cutv);
    kC<<<TOKENS / 256, 256, 0, stream>>>(content, dvals, sumd, tau, cutv,
                                         (float*)d_out);
}